// Round 9
// baseline (691.485 us; speedup 1.0000x reference)
//
#include <hip/hip_runtime.h>
#include <stdint.h>

// Problem constants
#define L_SEQ 2048
#define BB 2
#define DD 1024
#define NH 16
#define SPAN 128

typedef __attribute__((ext_vector_type(8))) short short8;   // 8 x bf16 MFMA frag
typedef __attribute__((ext_vector_type(4))) float floatx4;  // MFMA acc / NT stores

__device__ __forceinline__ short f32_bf16(float f) {
  uint32_t u = __float_as_uint(f);
  u += 0x7FFFu + ((u >> 16) & 1u);   // RNE
  return (short)(u >> 16);
}
__device__ __forceinline__ float bf2f(short s) {
  return __uint_as_float(((uint32_t)(uint16_t)s) << 16);
}

// async 16B global->LDS (LDS dest = wave-uniform base + lane*16)
__device__ __forceinline__ void gld16(const short* g, short* l) {
  __builtin_amdgcn_global_load_lds(
      (__attribute__((address_space(1))) void*)(g),
      (__attribute__((address_space(3))) void*)(l), 16, 0, 0);
}

// ---------------- prep: convert q/k/v to bf16 + transpose-convert weights ---
// grid: 1536 convert blocks (8 float4 / thread) + 4*256 transpose blocks.
// NOTE: separate conversion pass is deliberate. Reading f32 A directly in the
// GEMM (reg-staged) regressed 32 us (round-3): load->16 MFMA(~80cy)->ds_write
// chain can't hide 200-500cy latency per k-step.
__global__ __launch_bounds__(256) void k_prep(
    const float* __restrict__ s0, const float* __restrict__ s1, const float* __restrict__ s2,
    const float* __restrict__ w0, const float* __restrict__ w1,
    const float* __restrict__ w2, const float* __restrict__ w3,
    short* __restrict__ d0, short* __restrict__ d1, short* __restrict__ d2,
    short* __restrict__ WT) {
  __shared__ float tile[64][65];
  int bid = blockIdx.x, tid = threadIdx.x;
  if (bid < 1536) {  // convert: 3 tensors x 512 blocks x (256 thr x 8 float4)
    int y = bid >> 9;  // 0..2
    const float* s = y == 0 ? s0 : (y == 1 ? s1 : s2);
    short* d = y == 0 ? d0 : (y == 1 ? d1 : d2);
    int i = (bid & 511) * 2048 + tid * 8;
#pragma unroll
    for (int j = 0; j < 8; ++j) {
      float4 v = ((const float4*)s)[i + j];
      short4 o;
      o.x = f32_bf16(v.x); o.y = f32_bf16(v.y); o.z = f32_bf16(v.z); o.w = f32_bf16(v.w);
      ((short4*)d)[i + j] = o;
    }
  } else {  // transpose: 4 weights x 256 blocks (64x64 tiles)
    int b2 = bid - 1536;
    int z = b2 >> 8;          // weight id
    int xy = b2 & 255;
    int bx = (xy & 15) * 64, by = (xy >> 4) * 64;
    int tx = tid & 63, ty = tid >> 6;  // (64,4)
    const float* src = z == 0 ? w0 : z == 1 ? w1 : z == 2 ? w2 : w3;
    short* out = WT + (size_t)z * (DD * DD);
#pragma unroll
    for (int r = 0; r < 64; r += 4)
      tile[ty + r][tx] = src[(size_t)(by + ty + r) * DD + bx + tx];
    __syncthreads();
    int r2 = tid >> 2, q = tid & 3;
    short8 o0, o1;
#pragma unroll
    for (int j = 0; j < 8; ++j) o0[j] = f32_bf16(tile[q * 16 + j][r2]);
#pragma unroll
    for (int j = 0; j < 8; ++j) o1[j] = f32_bf16(tile[q * 16 + 8 + j][r2]);
    *(short8*)(out + (size_t)(bx + r2) * DD + by + q * 16) = o0;
    *(short8*)(out + (size_t)(bx + r2) * DD + by + q * 16 + 8) = o1;
  }
}

// -------- 128x128 bf16 MFMA GEMM core, 2-phase pipelined over 32-col halves -
#define BM 128
#define BN 128
#define SMEM_SH 17408  // shorts: staging needs 16384; epilogue bounce needs 128*136

__device__ __forceinline__ void gemm_core(const short* __restrict__ A,
                                          const short* __restrict__ BT,
                                          floatx4 acc[4][4], int bm0, int bn0,
                                          short* smem) {
  int tid = threadIdx.x;
  int wave = tid >> 6, lane = tid & 63;
  int li = lane & 15, quad = lane >> 4;
  int wm = (wave & 1) * 64, wn = (wave >> 1) * 64;
  int r0 = wave * 32 + (lane >> 2);  // staging row; col (lane&3)*8
  int c0 = (lane & 3) * 8;
  const short* gA = A + (size_t)(bm0 + r0) * DD + c0;
  const short* gB = BT + (size_t)(bn0 + r0) * DD + c0;
  short* sA = smem;          // [2][4096]
  short* sB = smem + 8192;   // [2][4096]
  {
    short* lA = sA + wave * 1024;
    short* lB = sB + wave * 1024;
    gld16(gA, lA);
    gld16(gA + (size_t)16 * DD, lA + 512);
    gld16(gB, lB);
    gld16(gB + (size_t)16 * DD, lB + 512);
  }
  __syncthreads();
#pragma unroll 2
  for (int k = 0; k < 32; ++k) {
    int cur = k & 1;
    if (k < 31) {  // prefetch next half into the other buffer (overlaps MFMA)
      int koff = (k + 1) * 32;
      short* lA = sA + (cur ^ 1) * 4096 + wave * 1024;
      short* lB = sB + (cur ^ 1) * 4096 + wave * 1024;
      gld16(gA + koff, lA);
      gld16(gA + (size_t)16 * DD + koff, lA + 512);
      gld16(gB + koff, lB);
      gld16(gB + (size_t)16 * DD + koff, lB + 512);
    }
    const short* cA = sA + cur * 4096;
    const short* cB = sB + cur * 4096;
    short8 af[4], bf[4];
#pragma unroll
    for (int t = 0; t < 4; ++t) {
      af[t] = *(const short8*)&cA[(wm + t * 16 + li) * 32 + quad * 8];
      bf[t] = *(const short8*)&cB[(wn + t * 16 + li) * 32 + quad * 8];
    }
#pragma unroll
    for (int tm = 0; tm < 4; ++tm)
#pragma unroll
      for (int tn = 0; tn < 4; ++tn)
        acc[tm][tn] = __builtin_amdgcn_mfma_f32_16x16x32_bf16(af[tm], bf[tn], acc[tm][tn], 0, 0, 0);
    __syncthreads();  // reads of cur done; prefetch into cur^1 drained
  }
}

// ---------------- fused QKV projection GEMM (V written pre-transposed) ------
__global__ __launch_bounds__(256) void k_proj(
    const short* __restrict__ xq, const short* __restrict__ xk, const short* __restrict__ xv,
    const short* __restrict__ WT,
    const float* __restrict__ bq, const float* __restrict__ bk, const float* __restrict__ bv,
    short* __restrict__ qo, short* __restrict__ ko, short* __restrict__ vto) {
  __shared__ __attribute__((aligned(16))) short smem[SMEM_SH];
  // XCD-aware swizzle over (8,32,3) = 768 blocks
  int flat = (blockIdx.z * 32 + blockIdx.y) * 8 + blockIdx.x;
  int swz = (flat & 7) * 96 + (flat >> 3);
  int bxw = swz & 7, byw = (swz >> 3) & 31, mode = swz >> 8;
  const short* A = mode == 0 ? xq : (mode == 1 ? xk : xv);
  const short* BT = WT + (size_t)mode * DD * DD;
  const float* bias = mode == 0 ? bq : (mode == 1 ? bk : bv);
  floatx4 acc[4][4] = {};
  int bm0 = byw * BM, bn0 = bxw * BN;
  gemm_core(A, BT, acc, bm0, bn0, smem);

  int tid = threadIdx.x;
  int wave = tid >> 6, lane = tid & 63;
  int li = lane & 15, quad = lane >> 4;
  int wm = (wave & 1) * 64, wn = (wave >> 1) * 64;
  // bounce C tile through LDS (bf16, stride 136), then vectorized stores
#pragma unroll
  for (int tm = 0; tm < 4; ++tm)
#pragma unroll
    for (int tn = 0; tn < 4; ++tn) {
      int gn = bn0 + wn + tn * 16 + li;
      float bs = bias[gn];
#pragma unroll
      for (int r = 0; r < 4; ++r)
        smem[(wm + tm * 16 + quad * 4 + r) * 136 + wn + tn * 16 + li] =
            f32_bf16(acc[tm][tn][r] + bs);
    }
  __syncthreads();
  if (mode != 2) {
    // q/k: (h,b,l,dk) row-major 64-wide rows
    short* dst = (mode == 0) ? qo : ko;
    int row = tid >> 1, half = tid & 1;
    int gm = bm0 + row, l = gm >> 1, b = gm & 1;  // rows are l*B + b
    int h = (bn0 + half * 64) >> 6;
    short* drow = dst + (((size_t)h * BB + b) * L_SEQ + l) * 64;
#pragma unroll
    for (int j = 0; j < 8; ++j)
      *(short8*)(drow + j * 8) = *(const short8*)&smem[row * 136 + half * 64 + j * 8];
  } else {
    // v: write directly transposed (h,b,dv,l); contiguous along l per thread
    int col = tid & 127, b2 = tid >> 7;        // tile col, batch parity
    int h2 = (bn0 + col) >> 6, dv = (bn0 + col) & 63;
    int l0 = bm0 >> 1;
    short* drow = vto + (((size_t)h2 * BB + b2) * 64 + dv) * L_SEQ + l0;
#pragma unroll
    for (int u0 = 0; u0 < 64; u0 += 8) {
      short8 o;
#pragma unroll
      for (int j = 0; j < 8; ++j)
        o[j] = smem[(2 * (u0 + j) + b2) * 136 + col];
      *(short8*)(drow + u0) = o;
    }
  }
}

// ---------------- banded attention: block = 4 waves = 64 q rows -------------
// Zero-region stores (data-independent, wave-uniform tiles) are issued inside
// the QK^T loop with fully STATIC indexing (r5's retry minus the rule-#20
// scratch bug: no runtime-bounded loops, no runtime-indexed arrays). Band
// tiles (<=3/row) stay data-dependent and are interleaved into PV.
__global__ __launch_bounds__(256) void k_attn(
    const short* __restrict__ qw, const short* __restrict__ kw, const short* __restrict__ vTw,
    float* __restrict__ attn_out, short* __restrict__ ctx) {
  __shared__ short sbuf[20480];  // 40960 B: K0[320*32] | K1[320*32]; later P[4][16*296]
  short* K0 = sbuf;
  short* K1 = sbuf + 10240;
  const int tid = threadIdx.x;
  const int wv = tid >> 6, lane = tid & 63;
  const int li = lane & 15, quad = lane >> 4;
  // XCD swizzle: group same-hb, adjacent K-window blocks per XCD
  int flat = blockIdx.y * 32 + blockIdx.x;
  int swz = (flat & 7) * 128 + (flat >> 3);
  const int i0b = (swz & 31) * 64;
  const int hb = swz >> 5;    // h*B + b
  const int i0 = i0b + wv * 16;
  const int jb = i0b - SPAN;  // K window rows jb .. jb+319
  const short* Q = qw + (size_t)hb * L_SEQ * 64;
  const short* K = kw + (size_t)hb * L_SEQ * 64;
  const short* VT = vTw + (size_t)hb * 64 * L_SEQ;
  float* Aout = attn_out + (size_t)hb * L_SEQ * L_SEQ;

  // ---- stage K window: 40 wave-instrs (10/wave); lane-linear LDS layout ----
#pragma unroll
  for (int t = 0; t < 10; ++t) {
    int idx = wv + 4 * t;           // 0..39 (uniform per wave)
    int half = idx >= 20 ? 1 : 0;   // K0 / K1 (k-cols 0..31 / 32..63)
    int ridx = idx - half * 20;     // 0..19 -> rows ridx*16 .. +16
    int row = ridx * 16 + (lane >> 2);
    int jr = jb + row;
    int jc = jr < 0 ? 0 : (jr >= L_SEQ ? L_SEQ - 1 : jr);  // clamp (masked later)
    const short* g = K + (size_t)jc * 64 + half * 32 + (lane & 3) * 8;
    short* l = (half ? K1 : K0) + ridx * 16 * 32;  // wave-uniform base
    gld16(g, l);
  }

  short8 qf0 = *(const short8*)(Q + (size_t)(i0 + li) * 64 + quad * 8);
  short8 qf1 = *(const short8*)(Q + (size_t)(i0 + li) * 64 + 32 + quad * 8);

  // band tile range (wave-uniform): 256-col tiles touching [jbase, jbase+288)
  const int jbase = i0 - SPAN;  // = jb + wv*16
  const int bandlo = jbase < 0 ? 0 : jbase;
  int bandhi = jbase + 287; if (bandhi > L_SEQ - 1) bandhi = L_SEQ - 1;
  const int itlo = bandlo >> 8, ithi = bandhi >> 8;

  __syncthreads();  // K staged

  // ---- S = Q K^T over the 17-tile strip; zero-tile stores interleaved ----
  // Iteration t<16 covers tile it=t>>1, rows (t&1)*8..+8 (static indices;
  // (it<itlo||it>ithi) is wave-uniform -> cheap scalar branch).
  floatx4 S[17];
  const floatx4 zv4 = {0.f, 0.f, 0.f, 0.f};
  __builtin_amdgcn_s_setprio(1);
#pragma unroll
  for (int t = 0; t < 17; ++t) {
    int j0 = jbase + t * 16;
    floatx4 acc = {0.f, 0.f, 0.f, 0.f};
    if (j0 > -16 && j0 < L_SEQ) {
      int jrel = (wv + t) * 16;
      short8 kf0 = *(const short8*)&K0[(jrel + li) * 32 + quad * 8];
      short8 kf1 = *(const short8*)&K1[(jrel + li) * 32 + quad * 8];
      acc = __builtin_amdgcn_mfma_f32_16x16x32_bf16(qf0, kf0, acc, 0, 0, 0);
      acc = __builtin_amdgcn_mfma_f32_16x16x32_bf16(qf1, kf1, acc, 0, 0, 0);
    }
    S[t] = acc;
    if (t < 16) {
      const int it = t >> 1, rbase = (t & 1) * 8;
      if (it < itlo || it > ithi) {
        float* zb = Aout + (size_t)(i0 + rbase) * L_SEQ + it * 256 + lane * 4;
#pragma unroll
        for (int rr = 0; rr < 8; ++rr)
          __builtin_nontemporal_store(zv4, (floatx4*)(zb + (size_t)rr * L_SEQ));
      }
    }
  }
  __builtin_amdgcn_s_setprio(0);
  // scale + band mask + row max  (C-layout: row = quad*4+r, col = li)
  float mrow[4] = {-1e30f, -1e30f, -1e30f, -1e30f};
#pragma unroll
  for (int t = 0; t < 17; ++t) {
    int j = jbase + t * 16 + li;
#pragma unroll
    for (int r = 0; r < 4; ++r) {
      int i = i0 + quad * 4 + r;
      bool inband = (j >= i - SPAN) && (j <= i + SPAN) && (j >= 0) && (j < L_SEQ);
      float s = inband ? S[t][r] * 0.125f : -1e30f;
      S[t][r] = s;
      mrow[r] = fmaxf(mrow[r], s);
    }
  }
#pragma unroll
  for (int m = 1; m <= 8; m <<= 1)
#pragma unroll
    for (int r = 0; r < 4; ++r) mrow[r] = fmaxf(mrow[r], __shfl_xor(mrow[r], m));
  float lsum[4] = {0.f, 0.f, 0.f, 0.f};
#pragma unroll
  for (int t = 0; t < 17; ++t)
#pragma unroll
    for (int r = 0; r < 4; ++r) {
      float p = __expf(S[t][r] - mrow[r]);
      S[t][r] = p;
      lsum[r] += p;
    }
#pragma unroll
  for (int m = 1; m <= 8; m <<= 1)
#pragma unroll
    for (int r = 0; r < 4; ++r) lsum[r] += __shfl_xor(lsum[r], m);
  float inv[4];
#pragma unroll
  for (int r = 0; r < 4; ++r) inv[r] = 1.0f / lsum[r];

  __syncthreads();  // all waves done reading K -> reuse sbuf for P strips
  short* myP = sbuf + wv * 4736;  // 16 rows x 296 (288 + 8 pad) shorts
#pragma unroll
  for (int t = 0; t < 17; ++t)
#pragma unroll
    for (int r = 0; r < 4; ++r)
      myP[(quad * 4 + r) * 296 + t * 16 + li] = f32_bf16(S[t][r] * inv[r]);
  // zero pad cols 272..287
  *(short4*)&myP[(lane >> 2) * 296 + 272 + (lane & 3) * 4] = short4{0, 0, 0, 0};
  __syncthreads();

  // ---- O = P (16x288) x V (288x64), band-tile stores interleaved ----------
  floatx4 O[4] = {};
#pragma unroll
  for (int c = 0; c < 9; ++c) {
    short8 pf = *(const short8*)&myP[li * 296 + c * 32 + quad * 8];
    int jg = jbase + c * 32 + quad * 8;
    int jc = (jg >= 0 && jg < L_SEQ) ? jg : 0;  // clamp: P is 0 there anyway
    short8 vf[4];
#pragma unroll
    for (int n = 0; n < 4; ++n)
      vf[n] = *(const short8*)(VT + (size_t)(n * 16 + li) * L_SEQ + jc);
    // interleaved band stores: rows 2c, 2c+1, tiles itlo..ithi only
    if (c < 8) {
#pragma unroll
      for (int rr = 0; rr < 2; ++rr) {
        int row = c * 2 + rr;
        float* orow = Aout + (size_t)(i0 + row) * L_SEQ;
        const short* prow = &myP[row * 296];
        for (int it = itlo; it <= ithi; ++it) {
          int col = it * 256 + lane * 4;
          int s = col - jbase;
          floatx4 v = {0.f, 0.f, 0.f, 0.f};
          if (s >= 0 && s < 288) {
            short4 p4 = *(const short4*)(prow + s);
            v.x = bf2f(p4.x); v.y = bf2f(p4.y); v.z = bf2f(p4.z); v.w = bf2f(p4.w);
          }
          __builtin_nontemporal_store(v, (floatx4*)(orow + col));
        }
      }
    }
#pragma unroll
    for (int n = 0; n < 4; ++n)
      O[n] = __builtin_amdgcn_mfma_f32_16x16x32_bf16(pf, vf[n], O[n], 0, 0, 0);
  }
  const int b = hb & 1, h = hb >> 1;
#pragma unroll
  for (int n = 0; n < 4; ++n)
#pragma unroll
    for (int r = 0; r < 4; ++r) {
      int irow = quad * 4 + r;
      ctx[((size_t)(i0 + irow) * BB + b) * DD + h * 64 + n * 16 + li] = f32_bf16(O[n][r]);
    }
}

// ---------------- FC GEMM + bias + residual (bf16 output) --------------------
__global__ __launch_bounds__(256) void k_fc(
    const short* __restrict__ ctx, const short* __restrict__ WfcT,
    const float* __restrict__ bfc, const float* __restrict__ query,
    short* __restrict__ ypre) {
  __shared__ __attribute__((aligned(16))) short smem[SMEM_SH];
  // XCD swizzle over (8,32) = 256 blocks
  int flat = blockIdx.y * 8 + blockIdx.x;
  int swz = (flat & 7) * 32 + (flat >> 3);
  int bm0 = (swz >> 3) * BM, bn0 = (swz & 7) * BN;
  floatx4 acc[4][4] = {};
  gemm_core(ctx, WfcT, acc, bm0, bn0, smem);
  int tid = threadIdx.x;
  int wave = tid >> 6, lane = tid & 63;
  int li = lane & 15, quad = lane >> 4;
  int wm = (wave & 1) * 64, wn = (wave >> 1) * 64;
  // bf16 bounce (y = fc + bias + residual), stride 136
#pragma unroll
  for (int tm = 0; tm < 4; ++tm)
#pragma unroll
    for (int tn = 0; tn < 4; ++tn) {
      int gn = bn0 + wn + tn * 16 + li;
      float bs = bfc[gn];
#pragma unroll
      for (int r = 0; r < 4; ++r) {
        int gm = bm0 + wm + tm * 16 + quad * 4 + r;
        smem[(wm + tm * 16 + quad * 4 + r) * 136 + wn + tn * 16 + li] =
            f32_bf16(acc[tm][tn][r] + bs + query[(size_t)gm * DD + gn]);
      }
    }
  __syncthreads();
  int row = tid >> 1, half = tid & 1;
  int gm = bm0 + row;
  short* drow = ypre + (size_t)gm * DD + bn0 + half * 64;
#pragma unroll
  for (int j = 0; j < 8; ++j)
    *(short8*)(drow + j * 8) = *(const short8*)&smem[row * 136 + half * 64 + j * 8];
}

// ---------------- LayerNorm (bf16 input) -------------------------------------
__global__ __launch_bounds__(256) void k_ln(
    const short* __restrict__ yp, const float* __restrict__ gamma,
    const float* __restrict__ beta, float* __restrict__ out) {
  __shared__ float red[8];
  int row = blockIdx.x, tid = threadIdx.x;
  short4 h4 = ((const short4*)(yp + (size_t)row * DD))[tid];
  float4 v;
  v.x = bf2f(h4.x); v.y = bf2f(h4.y); v.z = bf2f(h4.z); v.w = bf2f(h4.w);
  float s = v.x + v.y + v.z + v.w;
  float s2 = v.x * v.x + v.y * v.y + v.z * v.z + v.w * v.w;
#pragma unroll
  for (int m = 1; m <= 32; m <<= 1) {
    s += __shfl_xor(s, m);
    s2 += __shfl_xor(s2, m);
  }
  int wv = tid >> 6;
  if ((tid & 63) == 0) { red[wv] = s; red[wv + 4] = s2; }
  __syncthreads();
  s = red[0] + red[1] + red[2] + red[3];
  s2 = red[4] + red[5] + red[6] + red[7];
  float mu = s * (1.0f / DD);
  float var = s2 * (1.0f / DD) - mu * mu;
  float rs = rsqrtf(var + 1e-5f);
  float4 g = ((const float4*)gamma)[tid];
  float4 bb = ((const float4*)beta)[tid];
  float4 o;
  o.x = (v.x - mu) * rs * g.x + bb.x;
  o.y = (v.y - mu) * rs * g.y + bb.y;
  o.z = (v.z - mu) * rs * g.z + bb.z;
  o.w = (v.w - mu) * rs * g.w + bb.w;
  ((float4*)(out + (size_t)row * DD))[tid] = o;
}

// ---------------- launch -----------------------------------------------------
extern "C" void kernel_launch(void* const* d_in, const int* in_sizes, int n_in,
                              void* d_out, int out_size, void* d_ws, size_t ws_size,
                              hipStream_t stream) {
  const float* query = (const float*)d_in[0];
  const float* key   = (const float*)d_in[1];
  const float* value = (const float*)d_in[2];
  const float* Wq    = (const float*)d_in[3];
  const float* bq    = (const float*)d_in[4];
  const float* Wk    = (const float*)d_in[5];
  const float* bk    = (const float*)d_in[6];
  const float* Wv    = (const float*)d_in[7];
  const float* bv    = (const float*)d_in[8];
  const float* Wfc   = (const float*)d_in[9];
  const float* bfc   = (const float*)d_in[10];
  const float* gamma = (const float*)d_in[11];
  const float* beta  = (const float*)d_in[12];
  float* out = (float*)d_out;
  float* attn = out + (size_t)L_SEQ * BB * DD;  // y first (4194304), then attn

  // workspace layout (80 MB)
  char* w = (char*)d_ws;
  short* xq_b  = (short*)(w);
  short* xk_b  = (short*)(w + ((size_t)8 << 20));
  short* xv_b  = (short*)(w + ((size_t)16 << 20));
  short* WT    = (short*)(w + ((size_t)24 << 20));  // WqT,WkT,WvT,WfcT bf16 (2MB each)
  short* q_ws  = (short*)(w + ((size_t)32 << 20));
  short* k_ws  = (short*)(w + ((size_t)40 << 20));
  short* vT_ws = (short*)(w + ((size_t)56 << 20));
  short* ctx   = (short*)(w + ((size_t)64 << 20));
  short* ypre  = (short*)(w + ((size_t)72 << 20));  // bf16 y (8 MB)

  k_prep<<<2560, 256, 0, stream>>>(query, key, value, Wq, Wk, Wv, Wfc,
                                   xq_b, xk_b, xv_b, WT);
  k_proj<<<dim3(8, 32, 3), 256, 0, stream>>>(xq_b, xk_b, xv_b, WT, bq, bk, bv, q_ws, k_ws, vT_ws);
  k_attn<<<dim3(32, 32), 256, 0, stream>>>(q_ws, k_ws, vT_ws, attn, ctx);
  k_fc<<<dim3(8, 32), 256, 0, stream>>>(ctx, WT + (size_t)3 * DD * DD, bfc, query, ypre);
  k_ln<<<4096, 256, 0, stream>>>(ypre, gamma, beta, out);
}

// Round 10
// 688.641 us; speedup vs baseline: 1.0041x; 1.0041x over previous
//
#include <hip/hip_runtime.h>
#include <stdint.h>

// Problem constants
#define L_SEQ 2048
#define BB 2
#define DD 1024
#define NH 16
#define SPAN 128

typedef __attribute__((ext_vector_type(8))) short short8;   // 8 x bf16 MFMA frag
typedef __attribute__((ext_vector_type(4))) float floatx4;  // MFMA acc / stores

__device__ __forceinline__ short f32_bf16(float f) {
  uint32_t u = __float_as_uint(f);
  u += 0x7FFFu + ((u >> 16) & 1u);   // RNE
  return (short)(u >> 16);
}
__device__ __forceinline__ float bf2f(short s) {
  return __uint_as_float(((uint32_t)(uint16_t)s) << 16);
}

// async 16B global->LDS (LDS dest = wave-uniform base + lane*16)
__device__ __forceinline__ void gld16(const short* g, short* l) {
  __builtin_amdgcn_global_load_lds(
      (__attribute__((address_space(1))) void*)(g),
      (__attribute__((address_space(3))) void*)(l), 16, 0, 0);
}

// ---------------- prep: convert q/k/v to bf16 + transpose-convert weights ---
// grid: 1536 convert blocks (8 float4 / thread) + 4*256 transpose blocks.
// NOTE: separate conversion pass is deliberate. Reading f32 A directly in the
// GEMM (reg-staged) regressed 32 us (round-3): load->16 MFMA(~80cy)->ds_write
// chain can't hide 200-500cy latency per k-step.
__global__ __launch_bounds__(256) void k_prep(
    const float* __restrict__ s0, const float* __restrict__ s1, const float* __restrict__ s2,
    const float* __restrict__ w0, const float* __restrict__ w1,
    const float* __restrict__ w2, const float* __restrict__ w3,
    short* __restrict__ d0, short* __restrict__ d1, short* __restrict__ d2,
    short* __restrict__ WT) {
  __shared__ float tile[64][65];
  int bid = blockIdx.x, tid = threadIdx.x;
  if (bid < 1536) {  // convert: 3 tensors x 512 blocks x (256 thr x 8 float4)
    int y = bid >> 9;  // 0..2
    const float* s = y == 0 ? s0 : (y == 1 ? s1 : s2);
    short* d = y == 0 ? d0 : (y == 1 ? d1 : d2);
    int i = (bid & 511) * 2048 + tid * 8;
#pragma unroll
    for (int j = 0; j < 8; ++j) {
      float4 v = ((const float4*)s)[i + j];
      short4 o;
      o.x = f32_bf16(v.x); o.y = f32_bf16(v.y); o.z = f32_bf16(v.z); o.w = f32_bf16(v.w);
      ((short4*)d)[i + j] = o;
    }
  } else {  // transpose: 4 weights x 256 blocks (64x64 tiles)
    int b2 = bid - 1536;
    int z = b2 >> 8;          // weight id
    int xy = b2 & 255;
    int bx = (xy & 15) * 64, by = (xy >> 4) * 64;
    int tx = tid & 63, ty = tid >> 6;  // (64,4)
    const float* src = z == 0 ? w0 : z == 1 ? w1 : z == 2 ? w2 : w3;
    short* out = WT + (size_t)z * (DD * DD);
#pragma unroll
    for (int r = 0; r < 64; r += 4)
      tile[ty + r][tx] = src[(size_t)(by + ty + r) * DD + bx + tx];
    __syncthreads();
    int r2 = tid >> 2, q = tid & 3;
    short8 o0, o1;
#pragma unroll
    for (int j = 0; j < 8; ++j) o0[j] = f32_bf16(tile[q * 16 + j][r2]);
#pragma unroll
    for (int j = 0; j < 8; ++j) o1[j] = f32_bf16(tile[q * 16 + 8 + j][r2]);
    *(short8*)(out + (size_t)(bx + r2) * DD + by + q * 16) = o0;
    *(short8*)(out + (size_t)(bx + r2) * DD + by + q * 16 + 8) = o1;
  }
}

// -------- 128x128 bf16 MFMA GEMM core, 2-phase pipelined over 32-col halves -
#define BM 128
#define BN 128
#define SMEM_SH 17408  // shorts: staging needs 16384; epilogue bounce needs 128*136

__device__ __forceinline__ void gemm_core(const short* __restrict__ A,
                                          const short* __restrict__ BT,
                                          floatx4 acc[4][4], int bm0, int bn0,
                                          short* smem) {
  int tid = threadIdx.x;
  int wave = tid >> 6, lane = tid & 63;
  int li = lane & 15, quad = lane >> 4;
  int wm = (wave & 1) * 64, wn = (wave >> 1) * 64;
  int r0 = wave * 32 + (lane >> 2);  // staging row; col (lane&3)*8
  int c0 = (lane & 3) * 8;
  const short* gA = A + (size_t)(bm0 + r0) * DD + c0;
  const short* gB = BT + (size_t)(bn0 + r0) * DD + c0;
  short* sA = smem;          // [2][4096]
  short* sB = smem + 8192;   // [2][4096]
  {
    short* lA = sA + wave * 1024;
    short* lB = sB + wave * 1024;
    gld16(gA, lA);
    gld16(gA + (size_t)16 * DD, lA + 512);
    gld16(gB, lB);
    gld16(gB + (size_t)16 * DD, lB + 512);
  }
  __syncthreads();
#pragma unroll 2
  for (int k = 0; k < 32; ++k) {
    int cur = k & 1;
    if (k < 31) {  // prefetch next half into the other buffer (overlaps MFMA)
      int koff = (k + 1) * 32;
      short* lA = sA + (cur ^ 1) * 4096 + wave * 1024;
      short* lB = sB + (cur ^ 1) * 4096 + wave * 1024;
      gld16(gA + koff, lA);
      gld16(gA + (size_t)16 * DD + koff, lA + 512);
      gld16(gB + koff, lB);
      gld16(gB + (size_t)16 * DD + koff, lB + 512);
    }
    const short* cA = sA + cur * 4096;
    const short* cB = sB + cur * 4096;
    short8 af[4], bf[4];
#pragma unroll
    for (int t = 0; t < 4; ++t) {
      af[t] = *(const short8*)&cA[(wm + t * 16 + li) * 32 + quad * 8];
      bf[t] = *(const short8*)&cB[(wn + t * 16 + li) * 32 + quad * 8];
    }
#pragma unroll
    for (int tm = 0; tm < 4; ++tm)
#pragma unroll
      for (int tn = 0; tn < 4; ++tn)
        acc[tm][tn] = __builtin_amdgcn_mfma_f32_16x16x32_bf16(af[tm], bf[tn], acc[tm][tn], 0, 0, 0);
    __syncthreads();  // reads of cur done; prefetch into cur^1 drained
  }
}

// ---------------- fused QKV projection GEMM (V written pre-transposed) ------
__global__ __launch_bounds__(256) void k_proj(
    const short* __restrict__ xq, const short* __restrict__ xk, const short* __restrict__ xv,
    const short* __restrict__ WT,
    const float* __restrict__ bq, const float* __restrict__ bk, const float* __restrict__ bv,
    short* __restrict__ qo, short* __restrict__ ko, short* __restrict__ vto) {
  __shared__ __attribute__((aligned(16))) short smem[SMEM_SH];
  // XCD-aware swizzle over (8,32,3) = 768 blocks
  int flat = (blockIdx.z * 32 + blockIdx.y) * 8 + blockIdx.x;
  int swz = (flat & 7) * 96 + (flat >> 3);
  int bxw = swz & 7, byw = (swz >> 3) & 31, mode = swz >> 8;
  const short* A = mode == 0 ? xq : (mode == 1 ? xk : xv);
  const short* BT = WT + (size_t)mode * DD * DD;
  const float* bias = mode == 0 ? bq : (mode == 1 ? bk : bv);
  floatx4 acc[4][4] = {};
  int bm0 = byw * BM, bn0 = bxw * BN;
  gemm_core(A, BT, acc, bm0, bn0, smem);

  int tid = threadIdx.x;
  int wave = tid >> 6, lane = tid & 63;
  int li = lane & 15, quad = lane >> 4;
  int wm = (wave & 1) * 64, wn = (wave >> 1) * 64;
  // bounce C tile through LDS (bf16, stride 136), then vectorized stores
#pragma unroll
  for (int tm = 0; tm < 4; ++tm)
#pragma unroll
    for (int tn = 0; tn < 4; ++tn) {
      int gn = bn0 + wn + tn * 16 + li;
      float bs = bias[gn];
#pragma unroll
      for (int r = 0; r < 4; ++r)
        smem[(wm + tm * 16 + quad * 4 + r) * 136 + wn + tn * 16 + li] =
            f32_bf16(acc[tm][tn][r] + bs);
    }
  __syncthreads();
  if (mode != 2) {
    // q/k: (h,b,l,dk) row-major 64-wide rows
    short* dst = (mode == 0) ? qo : ko;
    int row = tid >> 1, half = tid & 1;
    int gm = bm0 + row, l = gm >> 1, b = gm & 1;  // rows are l*B + b
    int h = (bn0 + half * 64) >> 6;
    short* drow = dst + (((size_t)h * BB + b) * L_SEQ + l) * 64;
#pragma unroll
    for (int j = 0; j < 8; ++j)
      *(short8*)(drow + j * 8) = *(const short8*)&smem[row * 136 + half * 64 + j * 8];
  } else {
    // v: write directly transposed (h,b,dv,l); contiguous along l per thread
    int col = tid & 127, b2 = tid >> 7;        // tile col, batch parity
    int h2 = (bn0 + col) >> 6, dv = (bn0 + col) & 63;
    int l0 = bm0 >> 1;
    short* drow = vto + (((size_t)h2 * BB + b2) * 64 + dv) * L_SEQ + l0;
#pragma unroll
    for (int u0 = 0; u0 < 64; u0 += 8) {
      short8 o;
#pragma unroll
      for (int j = 0; j < 8; ++j)
        o[j] = smem[(2 * (u0 + j) + b2) * 136 + col];
      *(short8*)(drow + u0) = o;
    }
  }
}

// ---------------- banded attention: block = 4 waves = 64 q rows -------------
// r4/r7 structure. Store PLACEMENT is a proven dead lever (r4/r5/r6/r9 all
// flat) -> this round A/Bs store TYPE: regular cached stores instead of
// nontemporal. Hypothesis: gfx950 NT path commits at ~4.4 TB/s (bypasses L2
// write-combine); regular stores should match the fill's 6.3 TB/s.
__global__ __launch_bounds__(256) void k_attn(
    const short* __restrict__ qw, const short* __restrict__ kw, const short* __restrict__ vTw,
    float* __restrict__ attn_out, short* __restrict__ ctx) {
  __shared__ short sbuf[20480];  // 40960 B: K0[320*32] | K1[320*32]; later P[4][16*296]
  short* K0 = sbuf;
  short* K1 = sbuf + 10240;
  const int tid = threadIdx.x;
  const int wv = tid >> 6, lane = tid & 63;
  const int li = lane & 15, quad = lane >> 4;
  // XCD swizzle: group same-hb, adjacent K-window blocks per XCD
  int flat = blockIdx.y * 32 + blockIdx.x;
  int swz = (flat & 7) * 128 + (flat >> 3);
  const int i0b = (swz & 31) * 64;
  const int hb = swz >> 5;    // h*B + b
  const int i0 = i0b + wv * 16;
  const int jb = i0b - SPAN;  // K window rows jb .. jb+319
  const short* Q = qw + (size_t)hb * L_SEQ * 64;
  const short* K = kw + (size_t)hb * L_SEQ * 64;
  const short* VT = vTw + (size_t)hb * 64 * L_SEQ;
  float* Aout = attn_out + (size_t)hb * L_SEQ * L_SEQ;

  // ---- stage K window: 40 wave-instrs (10/wave); lane-linear LDS layout ----
#pragma unroll
  for (int t = 0; t < 10; ++t) {
    int idx = wv + 4 * t;           // 0..39 (uniform per wave)
    int half = idx >= 20 ? 1 : 0;   // K0 / K1 (k-cols 0..31 / 32..63)
    int ridx = idx - half * 20;     // 0..19 -> rows ridx*16 .. +16
    int row = ridx * 16 + (lane >> 2);
    int jr = jb + row;
    int jc = jr < 0 ? 0 : (jr >= L_SEQ ? L_SEQ - 1 : jr);  // clamp (masked later)
    const short* g = K + (size_t)jc * 64 + half * 32 + (lane & 3) * 8;
    short* l = (half ? K1 : K0) + ridx * 16 * 32;  // wave-uniform base
    gld16(g, l);
  }

  short8 qf0 = *(const short8*)(Q + (size_t)(i0 + li) * 64 + quad * 8);
  short8 qf1 = *(const short8*)(Q + (size_t)(i0 + li) * 64 + 32 + quad * 8);
  __syncthreads();  // K staged

  // ---- S = Q K^T over the 17-tile strip, frags from LDS ----
  floatx4 S[17];
  const int jbase = i0 - SPAN;  // = jb + wv*16
  __builtin_amdgcn_s_setprio(1);
#pragma unroll
  for (int t = 0; t < 17; ++t) {
    int j0 = jbase + t * 16;
    floatx4 acc = {0.f, 0.f, 0.f, 0.f};
    if (j0 > -16 && j0 < L_SEQ) {
      int jrel = (wv + t) * 16;
      short8 kf0 = *(const short8*)&K0[(jrel + li) * 32 + quad * 8];
      short8 kf1 = *(const short8*)&K1[(jrel + li) * 32 + quad * 8];
      acc = __builtin_amdgcn_mfma_f32_16x16x32_bf16(qf0, kf0, acc, 0, 0, 0);
      acc = __builtin_amdgcn_mfma_f32_16x16x32_bf16(qf1, kf1, acc, 0, 0, 0);
    }
    S[t] = acc;
  }
  __builtin_amdgcn_s_setprio(0);
  // scale + band mask + row max  (C-layout: row = quad*4+r, col = li)
  float mrow[4] = {-1e30f, -1e30f, -1e30f, -1e30f};
#pragma unroll
  for (int t = 0; t < 17; ++t) {
    int j = jbase + t * 16 + li;
#pragma unroll
    for (int r = 0; r < 4; ++r) {
      int i = i0 + quad * 4 + r;
      bool inband = (j >= i - SPAN) && (j <= i + SPAN) && (j >= 0) && (j < L_SEQ);
      float s = inband ? S[t][r] * 0.125f : -1e30f;
      S[t][r] = s;
      mrow[r] = fmaxf(mrow[r], s);
    }
  }
#pragma unroll
  for (int m = 1; m <= 8; m <<= 1)
#pragma unroll
    for (int r = 0; r < 4; ++r) mrow[r] = fmaxf(mrow[r], __shfl_xor(mrow[r], m));
  float lsum[4] = {0.f, 0.f, 0.f, 0.f};
#pragma unroll
  for (int t = 0; t < 17; ++t)
#pragma unroll
    for (int r = 0; r < 4; ++r) {
      float p = __expf(S[t][r] - mrow[r]);
      S[t][r] = p;
      lsum[r] += p;
    }
#pragma unroll
  for (int m = 1; m <= 8; m <<= 1)
#pragma unroll
    for (int r = 0; r < 4; ++r) lsum[r] += __shfl_xor(lsum[r], m);
  float inv[4];
#pragma unroll
  for (int r = 0; r < 4; ++r) inv[r] = 1.0f / lsum[r];

  __syncthreads();  // all waves done reading K -> reuse sbuf for P strips
  short* myP = sbuf + wv * 4736;  // 16 rows x 296 (288 + 8 pad) shorts
#pragma unroll
  for (int t = 0; t < 17; ++t)
#pragma unroll
    for (int r = 0; r < 4; ++r)
      myP[(quad * 4 + r) * 296 + t * 16 + li] = f32_bf16(S[t][r] * inv[r]);
  // zero pad cols 272..287
  *(short4*)&myP[(lane >> 2) * 296 + 272 + (lane & 3) * 4] = short4{0, 0, 0, 0};
  __syncthreads();

  // ---- O = P (16x288) x V (288x64), with attn row-stores interleaved ------
  floatx4 O[4] = {};
#pragma unroll
  for (int c = 0; c < 9; ++c) {
    short8 pf = *(const short8*)&myP[li * 296 + c * 32 + quad * 8];
    int jg = jbase + c * 32 + quad * 8;
    int jc = (jg >= 0 && jg < L_SEQ) ? jg : 0;  // clamp: P is 0 there anyway
    short8 vf[4];
#pragma unroll
    for (int n = 0; n < 4; ++n)
      vf[n] = *(const short8*)(VT + (size_t)(n * 16 + li) * L_SEQ + jc);
    // interleaved attn writes: rows 2c, 2c+1 — REGULAR cached stores (A/B vs NT)
    if (c < 8) {
#pragma unroll
      for (int rr = 0; rr < 2; ++rr) {
        int row = c * 2 + rr;
        float* orow = Aout + (size_t)(i0 + row) * L_SEQ;
        const short* prow = &myP[row * 296];
#pragma unroll
        for (int it = 0; it < 8; ++it) {
          int col = it * 256 + lane * 4;
          int s = col - jbase;
          floatx4 v = {0.f, 0.f, 0.f, 0.f};
          if (s >= 0 && s < 288) {
            short4 p4 = *(const short4*)(prow + s);
            v.x = bf2f(p4.x); v.y = bf2f(p4.y); v.z = bf2f(p4.z); v.w = bf2f(p4.w);
          }
          *(floatx4*)(orow + col) = v;
        }
      }
    }
#pragma unroll
    for (int n = 0; n < 4; ++n)
      O[n] = __builtin_amdgcn_mfma_f32_16x16x32_bf16(pf, vf[n], O[n], 0, 0, 0);
  }
  const int b = hb & 1, h = hb >> 1;
#pragma unroll
  for (int n = 0; n < 4; ++n)
#pragma unroll
    for (int r = 0; r < 4; ++r) {
      int irow = quad * 4 + r;
      ctx[((size_t)(i0 + irow) * BB + b) * DD + h * 64 + n * 16 + li] = f32_bf16(O[n][r]);
    }
}

// ---------------- FC GEMM + bias + residual (bf16 output) --------------------
__global__ __launch_bounds__(256) void k_fc(
    const short* __restrict__ ctx, const short* __restrict__ WfcT,
    const float* __restrict__ bfc, const float* __restrict__ query,
    short* __restrict__ ypre) {
  __shared__ __attribute__((aligned(16))) short smem[SMEM_SH];
  // XCD swizzle over (8,32) = 256 blocks
  int flat = blockIdx.y * 8 + blockIdx.x;
  int swz = (flat & 7) * 32 + (flat >> 3);
  int bm0 = (swz >> 3) * BM, bn0 = (swz & 7) * BN;
  floatx4 acc[4][4] = {};
  gemm_core(ctx, WfcT, acc, bm0, bn0, smem);
  int tid = threadIdx.x;
  int wave = tid >> 6, lane = tid & 63;
  int li = lane & 15, quad = lane >> 4;
  int wm = (wave & 1) * 64, wn = (wave >> 1) * 64;
  // bf16 bounce (y = fc + bias + residual), stride 136
#pragma unroll
  for (int tm = 0; tm < 4; ++tm)
#pragma unroll
    for (int tn = 0; tn < 4; ++tn) {
      int gn = bn0 + wn + tn * 16 + li;
      float bs = bfc[gn];
#pragma unroll
      for (int r = 0; r < 4; ++r) {
        int gm = bm0 + wm + tm * 16 + quad * 4 + r;
        smem[(wm + tm * 16 + quad * 4 + r) * 136 + wn + tn * 16 + li] =
            f32_bf16(acc[tm][tn][r] + bs + query[(size_t)gm * DD + gn]);
      }
    }
  __syncthreads();
  int row = tid >> 1, half = tid & 1;
  int gm = bm0 + row;
  short* drow = ypre + (size_t)gm * DD + bn0 + half * 64;
#pragma unroll
  for (int j = 0; j < 8; ++j)
    *(short8*)(drow + j * 8) = *(const short8*)&smem[row * 136 + half * 64 + j * 8];
}

// ---------------- LayerNorm (bf16 input) -------------------------------------
__global__ __launch_bounds__(256) void k_ln(
    const short* __restrict__ yp, const float* __restrict__ gamma,
    const float* __restrict__ beta, float* __restrict__ out) {
  __shared__ float red[8];
  int row = blockIdx.x, tid = threadIdx.x;
  short4 h4 = ((const short4*)(yp + (size_t)row * DD))[tid];
  float4 v;
  v.x = bf2f(h4.x); v.y = bf2f(h4.y); v.z = bf2f(h4.z); v.w = bf2f(h4.w);
  float s = v.x + v.y + v.z + v.w;
  float s2 = v.x * v.x + v.y * v.y + v.z * v.z + v.w * v.w;
#pragma unroll
  for (int m = 1; m <= 32; m <<= 1) {
    s += __shfl_xor(s, m);
    s2 += __shfl_xor(s2, m);
  }
  int wv = tid >> 6;
  if ((tid & 63) == 0) { red[wv] = s; red[wv + 4] = s2; }
  __syncthreads();
  s = red[0] + red[1] + red[2] + red[3];
  s2 = red[4] + red[5] + red[6] + red[7];
  float mu = s * (1.0f / DD);
  float var = s2 * (1.0f / DD) - mu * mu;
  float rs = rsqrtf(var + 1e-5f);
  float4 g = ((const float4*)gamma)[tid];
  float4 bb = ((const float4*)beta)[tid];
  float4 o;
  o.x = (v.x - mu) * rs * g.x + bb.x;
  o.y = (v.y - mu) * rs * g.y + bb.y;
  o.z = (v.z - mu) * rs * g.z + bb.z;
  o.w = (v.w - mu) * rs * g.w + bb.w;
  ((float4*)(out + (size_t)row * DD))[tid] = o;
}

// ---------------- launch -----------------------------------------------------
extern "C" void kernel_launch(void* const* d_in, const int* in_sizes, int n_in,
                              void* d_out, int out_size, void* d_ws, size_t ws_size,
                              hipStream_t stream) {
  const float* query = (const float*)d_in[0];
  const float* key   = (const float*)d_in[1];
  const float* value = (const float*)d_in[2];
  const float* Wq    = (const float*)d_in[3];
  const float* bq    = (const float*)d_in[4];
  const float* Wk    = (const float*)d_in[5];
  const float* bk    = (const float*)d_in[6];
  const float* Wv    = (const float*)d_in[7];
  const float* bv    = (const float*)d_in[8];
  const float* Wfc   = (const float*)d_in[9];
  const float* bfc   = (const float*)d_in[10];
  const float* gamma = (const float*)d_in[11];
  const float* beta  = (const float*)d_in[12];
  float* out = (float*)d_out;
  float* attn = out + (size_t)L_SEQ * BB * DD;  // y first (4194304), then attn

  // workspace layout (80 MB)
  char* w = (char*)d_ws;
  short* xq_b  = (short*)(w);
  short* xk_b  = (short*)(w + ((size_t)8 << 20));
  short* xv_b  = (short*)(w + ((size_t)16 << 20));
  short* WT    = (short*)(w + ((size_t)24 << 20));  // WqT,WkT,WvT,WfcT bf16 (2MB each)
  short* q_ws  = (short*)(w + ((size_t)32 << 20));
  short* k_ws  = (short*)(w + ((size_t)40 << 20));
  short* vT_ws = (short*)(w + ((size_t)56 << 20));
  short* ctx   = (short*)(w + ((size_t)64 << 20));
  short* ypre  = (short*)(w + ((size_t)72 << 20));  // bf16 y (8 MB)

  k_prep<<<2560, 256, 0, stream>>>(query, key, value, Wq, Wk, Wv, Wfc,
                                   xq_b, xk_b, xv_b, WT);
  k_proj<<<dim3(8, 32, 3), 256, 0, stream>>>(xq_b, xk_b, xv_b, WT, bq, bk, bv, q_ws, k_ws, vT_ws);
  k_attn<<<dim3(32, 32), 256, 0, stream>>>(q_ws, k_ws, vT_ws, attn, ctx);
  k_fc<<<dim3(8, 32), 256, 0, stream>>>(ctx, WT + (size_t)3 * DD * DD, bfc, query, ypre);
  k_ln<<<4096, 256, 0, stream>>>(ypre, gamma, beta, out);
}